// Round 8
// baseline (40.532 us; speedup 1.0000x reference)
//
#include <hip/hip_runtime.h>
#include <hip/hip_bf16.h>

typedef __attribute__((ext_vector_type(8))) short short8;
typedef __attribute__((ext_vector_type(4))) float f32x4;

#define NBATCH 32
#define NT 512
#define NS 512
#define ND 1024
#define BM 128
#define BN 128
#define BK 64                /* elems per phase (2 MFMA k-depths) */
#define NK (ND / BK)         /* 16 phases */

__device__ __forceinline__ short f2bf(float f) {
    union { __hip_bfloat16 h; short s; } u;
    u.h = __float2bfloat16(f);
    return u.s;
}

__device__ __forceinline__ short8 cvt8(float4 a, float4 b) {
    short8 r;
    r[0] = f2bf(a.x); r[1] = f2bf(a.y); r[2] = f2bf(a.z); r[3] = f2bf(a.w);
    r[4] = f2bf(b.x); r[5] = f2bf(b.y); r[6] = f2bf(b.z); r[7] = f2bf(b.w);
    return r;
}

__device__ __forceinline__ float ssq4(float s, float4 a) {
    return fmaf(a.x, a.x, fmaf(a.y, a.y, fmaf(a.z, a.z, fmaf(a.w, a.w, s))));
}

// r5/r7 geometry (best: 39.3us) with HALVED phase count. 128x128 tile, 512
// threads = 8 waves (2x4), wave = 64x32 out via 4x2 frags of
// v_mfma_f32_16x16x32_bf16. BK=64 per phase -> 16 barriers + 16 lgkm drains
// instead of 32 (the counter-validated model says LDS-port floor ~20.5us and
// we run ~52% duty; r7 proved intra-phase scheduling is already optimal, so
// the residual idle is the per-phase drain+barrier convoy - this attacks
// exactly that). Single prefetch reg set (32 VGPR): at BK=64 the phase is
// ~2x longer, so a load issued in phase k is vmcnt-waited in phase k+1 -
// distance >= one full phase (~1000+cy) > HBM latency (the distance r2
// lacked). Staging map: thread owns 8-elem segment u=tid&7 of rows tid>>3
// and tid>>3+64 per operand; swizzle involution phys_u = u ^ (row&7) on
// write and read sides: per-16-lane-quarter both hit each 16B unit exactly
// 2x (2-way = free). Global loads: 8 consecutive lanes = 256B contiguous,
// fully coalesced. Unchanged, proven: bf16 cvt once at staging; raw
// s_barrier + lgkmcnt(0)-only fences (global loads never drained in-loop);
// fused row sum-of-squares (norms free); XCD-chunked 1D grid; setprio
// around MFMA.
__global__ __launch_bounds__(512, 4)
void paircos_mfma(const float* __restrict__ sup, const float* __restrict__ tgt,
                  float* __restrict__ out) {
    __shared__ __align__(16) short As[2][BM * BK]; // targets tiles (16KB each)
    __shared__ __align__(16) short Bs[2][BN * BK]; // supports tiles
    __shared__ float tn[BM];
    __shared__ float sn[BN];

    const int tid = threadIdx.x;
    // XCD-chunked bijective swizzle (512 blocks)
    const int l    = blockIdx.x;
    const int wgid = (l & 7) * 64 + (l >> 3);
    const int b    = wgid >> 4;
    const int til  = wgid & 15;
    const int bt0  = (til >> 2) * BM;
    const int bs0  = (til & 3) * BN;

    // staging: thread owns 8-elem segment seg of rows srow and srow+64
    const int seg  = tid & 7;  // 0..7
    const int srow = tid >> 3; // 0..63

    const float* gA = tgt + (size_t)b * NT * ND + (size_t)(bt0 + srow) * ND + seg * 8;
    const float* gB = sup + (size_t)b * NS * ND + (size_t)(bs0 + srow) * ND + seg * 8;

    const int wave = tid >> 6;
    const int lane = tid & 63;
    const int wr  = (wave >> 2) * 64;  // 0 or 64
    const int wc  = (wave & 3) * 32;   // 0,32,64,96
    const int lhi = lane >> 4;         // 0..3 (k-group of 8)
    const int llo = lane & 15;

    f32x4 acc[4][2];
#pragma unroll
    for (int m = 0; m < 4; ++m)
#pragma unroll
        for (int n = 0; n < 2; ++n)
            acc[m][n] = (f32x4){0.f, 0.f, 0.f, 0.f};

    float sqa0 = 0.f, sqa1 = 0.f, sqb0 = 0.f, sqb1 = 0.f;

    // single prefetch set: 2 float4 per row, 2 rows, 2 operands = 32 VGPR
    float4 pA0, pA1, pA2, pA3, pB0, pB1, pB2, pB3;

    // write offsets (shorts): row*BK + (seg ^ (row&7))*8 ; (srow+64)&7==srow&7
    const int pu   = (seg ^ (srow & 7)) * 8;
    const int offw0 = srow * BK + pu;
    const int offw1 = (srow + 64) * BK + pu;

#define LOADT(KK)                                                              \
    do {                                                                       \
        pA0 = *reinterpret_cast<const float4*>(gA + (KK) * BK);                \
        pA1 = *reinterpret_cast<const float4*>(gA + (KK) * BK + 4);            \
        pA2 = *reinterpret_cast<const float4*>(gA + (KK) * BK + 64 * ND);      \
        pA3 = *reinterpret_cast<const float4*>(gA + (KK) * BK + 64 * ND + 4);  \
        pB0 = *reinterpret_cast<const float4*>(gB + (KK) * BK);                \
        pB1 = *reinterpret_cast<const float4*>(gB + (KK) * BK + 4);            \
        pB2 = *reinterpret_cast<const float4*>(gB + (KK) * BK + 64 * ND);      \
        pB3 = *reinterpret_cast<const float4*>(gB + (KK) * BK + 64 * ND + 4);  \
    } while (0)

#define STORET(P)                                                              \
    do {                                                                       \
        sqa0 = ssq4(ssq4(sqa0, pA0), pA1);                                     \
        *reinterpret_cast<short8*>(&As[P][offw0]) = cvt8(pA0, pA1);            \
        sqa1 = ssq4(ssq4(sqa1, pA2), pA3);                                     \
        *reinterpret_cast<short8*>(&As[P][offw1]) = cvt8(pA2, pA3);            \
        sqb0 = ssq4(ssq4(sqb0, pB0), pB1);                                     \
        *reinterpret_cast<short8*>(&Bs[P][offw0]) = cvt8(pB0, pB1);            \
        sqb1 = ssq4(ssq4(sqb1, pB2), pB3);                                     \
        *reinterpret_cast<short8*>(&Bs[P][offw1]) = cvt8(pB2, pB3);            \
    } while (0)

    // frag read at k-half KS: logical unit q = KS*4+lhi, phys = q ^ (row&7)
#define FRAG_READ(P, KS)                                                       \
    do {                                                                       \
        _Pragma("unroll") for (int m = 0; m < 4; ++m) {                        \
            const int row = wr + m * 16 + llo;                                 \
            const int off = row * BK + ((((KS) * 4 + lhi) ^ (row & 7)) * 8);   \
            af[m] = *reinterpret_cast<const short8*>(&As[P][off]);             \
        }                                                                      \
        _Pragma("unroll") for (int n = 0; n < 2; ++n) {                        \
            const int row = wc + n * 16 + llo;                                 \
            const int off = row * BK + ((((KS) * 4 + lhi) ^ (row & 7)) * 8);   \
            bfr[n] = *reinterpret_cast<const short8*>(&Bs[P][off]);            \
        }                                                                      \
    } while (0)

#define MFMA_BLOCK()                                                           \
    do {                                                                       \
        __builtin_amdgcn_s_setprio(1);                                         \
        _Pragma("unroll") for (int m = 0; m < 4; ++m)                          \
            _Pragma("unroll") for (int n = 0; n < 2; ++n)                      \
                acc[m][n] = __builtin_amdgcn_mfma_f32_16x16x32_bf16(           \
                    af[m], bfr[n], acc[m][n], 0, 0, 0);                        \
        __builtin_amdgcn_s_setprio(0);                                         \
    } while (0)

    // fence: wave's ds ops done, barrier. No vmcnt drain - prefetch loads
    // stay in flight across phases.
#define PHASE_FENCE()                                                          \
    do {                                                                       \
        asm volatile("s_waitcnt lgkmcnt(0)" ::: "memory");                     \
        __builtin_amdgcn_s_barrier();                                          \
        asm volatile("" ::: "memory");                                         \
    } while (0)

    // prologue: tile0 -> buf0; set <- tile1
    LOADT(0);
    STORET(0);
    LOADT(1);
    PHASE_FENCE();

    for (int k = 0; k < NK; ++k) {
        const int cur = k & 1;
        short8 af[4], bfr[2];
        FRAG_READ(cur, 0);                 // half-0 reads first
        if (k + 1 < NK) STORET(cur ^ 1);   // set (tile k+1) -> other buf;
                                           // vmcnt wait = loads from phase k-1
        if (k + 2 < NK) LOADT(k + 2);      // refill set; waited next phase
        MFMA_BLOCK();                      // half-0 MFMA
        FRAG_READ(cur, 1);                 // half-1
        MFMA_BLOCK();
        PHASE_FENCE();
    }

    // norms: row's sumsq lives in its 8 seg-threads (consecutive lanes
    // sharing tid>>3); xor 1,2,4 reduces within the group
#pragma unroll
    for (int d = 1; d < 8; d <<= 1) {
        sqa0 += __shfl_xor(sqa0, d);
        sqa1 += __shfl_xor(sqa1, d);
        sqb0 += __shfl_xor(sqb0, d);
        sqb1 += __shfl_xor(sqb1, d);
    }
    if (seg == 0) {
        tn[srow]      = sqrtf(sqa0);
        tn[srow + 64] = sqrtf(sqa1);
        sn[srow]      = sqrtf(sqb0);
        sn[srow + 64] = sqrtf(sqb1);
    }
    __syncthreads();

    float* outp = out + (size_t)b * NT * NS;
#pragma unroll
    for (int m = 0; m < 4; ++m) {
        const int lr0 = wr + m * 16 + lhi * 4;
#pragma unroll
        for (int n = 0; n < 2; ++n) {
            const int lc = wc + n * 16 + llo;
            const float snv = sn[lc];
            const int col = bs0 + lc;
#pragma unroll
            for (int j = 0; j < 4; ++j) {
                const float denom = fmaxf(tn[lr0 + j] * snv, 1e-10f);
                outp[(size_t)(bt0 + lr0 + j) * NS + col] =
                    acc[m][n][j] / denom * 0.5f + 0.5f;
            }
        }
    }
}

extern "C" void kernel_launch(void* const* d_in, const int* in_sizes, int n_in,
                              void* d_out, int out_size, void* d_ws, size_t ws_size,
                              hipStream_t stream) {
    const float* sup = (const float*)d_in[0]; // supports [32,512,1024]
    const float* tgt = (const float*)d_in[1]; // targets  [32,512,1024]
    float* out = (float*)d_out;               // [32,512,512] f32
    (void)in_sizes; (void)n_in; (void)out_size; (void)d_ws; (void)ws_size;
    paircos_mfma<<<dim3(16 * NBATCH), 512, 0, stream>>>(sup, tgt, out);
}

// Round 9
// 40.096 us; speedup vs baseline: 1.0109x; 1.0109x over previous
//
#include <hip/hip_runtime.h>
#include <hip/hip_bf16.h>

typedef __attribute__((ext_vector_type(8))) short short8;
typedef __attribute__((ext_vector_type(4))) float f32x4;

#define NBATCH 32
#define NT 512
#define NS 512
#define ND 1024
#define BM 128
#define BN 128
#define BK 32                /* elems per phase (one MFMA k-depth) */
#define NK (ND / BK)         /* 32 phases */
#define TSZ (BM * BK)        /* 4096 shorts per tile buffer */

__device__ __forceinline__ short f2bf(float f) {
    union { __hip_bfloat16 h; short s; } u;
    u.h = __float2bfloat16(f);
    return u.s;
}

__device__ __forceinline__ short8 cvt8(float4 a, float4 b) {
    short8 r;
    r[0] = f2bf(a.x); r[1] = f2bf(a.y); r[2] = f2bf(a.z); r[3] = f2bf(a.w);
    r[4] = f2bf(b.x); r[5] = f2bf(b.y); r[6] = f2bf(b.z); r[7] = f2bf(b.w);
    return r;
}

__device__ __forceinline__ float ssq4(float s, float4 a) {
    return fmaf(a.x, a.x, fmaf(a.y, a.y, fmaf(a.z, a.z, fmaf(a.w, a.w, s))));
}

// r5/r7 geometry (best: 39.3us) + CROSS-BARRIER FRAGMENT PREFETCH.
// Diagnosis (r6/r7/r8): every phase starts with all 16 waves/CU slamming
// ~96 ds_read_b128 at the LDS port and every wave's first MFMA waits
// through that queue (~400+cy dead zone x 32 phases) - port duty stuck at
// ~52% regardless of fence count or intra-phase order, because with double
// buffering the reads MUST follow the barrier (buffer written last phase).
// Fix: TRIPLE-buffer the tiles so tile k+1 is stable during phase k; each
// phase then MFMAs tile k purely from registers (fragments prefetched last
// phase - no ds dependency at phase start) while issuing tile k+1's frag
// reads (needed only after the next barrier -> full phase of latency
// slack), STORET tile k+2 -> buf[(k+2)%3], LOADT tile k+3 -> reg set.
// Single prefetch reg set: vmcnt-wait distance ~1 phase (>= HBM latency;
// r2's real killer was __syncthreads' vmcnt(0) drain, removed since r5).
// Unchanged, proven: 512 thr = 8 waves (2x4), wave 64x32 via 4x2 frags of
// v_mfma_f32_16x16x32_bf16; bf16 cvt once at staging; lgkmcnt(0)-only
// s_barrier fences; swizzle (u + (row>>1))&3 both sides (0 conflicts);
// fused row sum-of-squares (norms free); XCD-chunked 1D grid.
__global__ __launch_bounds__(512, 4)
void paircos_mfma(const float* __restrict__ sup, const float* __restrict__ tgt,
                  float* __restrict__ out) {
    __shared__ __align__(16) short As[3 * TSZ]; // targets tiles (3 x 8KB)
    __shared__ __align__(16) short Bs[3 * TSZ]; // supports tiles
    __shared__ float tn[BM];
    __shared__ float sn[BN];

    const int tid = threadIdx.x;
    // XCD-chunked bijective swizzle (512 blocks)
    const int l    = blockIdx.x;
    const int wgid = (l & 7) * 64 + (l >> 3);
    const int b    = wgid >> 4;
    const int til  = wgid & 15;
    const int bt0  = (til >> 2) * BM;
    const int bs0  = (til & 3) * BN;

    // staging: thread owns the 8-elem segment seg (0..3) of row srow (0..127)
    const int seg  = tid & 3;
    const int srow = tid >> 2;

    const float* gA = tgt + (size_t)b * NT * ND + (size_t)(bt0 + srow) * ND + seg * 8;
    const float* gB = sup + (size_t)b * NS * ND + (size_t)(bs0 + srow) * ND + seg * 8;

    const int wave = tid >> 6;
    const int lane = tid & 63;
    const int wr  = (wave >> 2) * 64;  // 0 or 64
    const int wc  = (wave & 3) * 32;   // 0,32,64,96
    const int lhi = lane >> 4;         // 0..3 (k-group of 8)
    const int llo = lane & 15;

    f32x4 acc[4][2];
#pragma unroll
    for (int m = 0; m < 4; ++m)
#pragma unroll
        for (int n = 0; n < 2; ++n)
            acc[m][n] = (f32x4){0.f, 0.f, 0.f, 0.f};

    float sqa = 0.f, sqb = 0.f;

    // single prefetch reg set (16 VGPR)
    float4 pA0, pA1, pB0, pB1;
    // two fragment sets (cross-barrier prefetch), static names (rule #20)
    short8 xa[4], xb[2], ya[4], yb[2];

    // staging LDS offset (shorts) within a buffer
    const int offw = srow * BK + (((seg + (srow >> 1)) & 3) * 8);

#define LOADT(KK)                                                              \
    do {                                                                       \
        pA0 = *reinterpret_cast<const float4*>(gA + (KK) * BK);                \
        pA1 = *reinterpret_cast<const float4*>(gA + (KK) * BK + 4);            \
        pB0 = *reinterpret_cast<const float4*>(gB + (KK) * BK);                \
        pB1 = *reinterpret_cast<const float4*>(gB + (KK) * BK + 4);            \
    } while (0)

#define STORET(WB)                                                             \
    do {                                                                       \
        sqa = ssq4(ssq4(sqa, pA0), pA1);                                       \
        *reinterpret_cast<short8*>(&As[(WB) + offw]) = cvt8(pA0, pA1);         \
        sqb = ssq4(ssq4(sqb, pB0), pB1);                                       \
        *reinterpret_cast<short8*>(&Bs[(WB) + offw]) = cvt8(pB0, pB1);         \
    } while (0)

#define FRAG_READ(FA, FB, RB)                                                  \
    do {                                                                       \
        _Pragma("unroll") for (int m = 0; m < 4; ++m) {                        \
            const int row = wr + m * 16 + llo;                                 \
            const int off = (RB) + row * BK + (((lhi + (row >> 1)) & 3) * 8);  \
            FA[m] = *reinterpret_cast<const short8*>(&As[off]);                \
        }                                                                      \
        _Pragma("unroll") for (int n = 0; n < 2; ++n) {                        \
            const int row = wc + n * 16 + llo;                                 \
            const int off = (RB) + row * BK + (((lhi + (row >> 1)) & 3) * 8);  \
            FB[n] = *reinterpret_cast<const short8*>(&Bs[off]);                \
        }                                                                      \
    } while (0)

#define MFMA_BLOCK(FA, FB)                                                     \
    do {                                                                       \
        __builtin_amdgcn_s_setprio(1);                                         \
        _Pragma("unroll") for (int m = 0; m < 4; ++m)                          \
            _Pragma("unroll") for (int n = 0; n < 2; ++n)                      \
                acc[m][n] = __builtin_amdgcn_mfma_f32_16x16x32_bf16(           \
                    FA[m], FB[n], acc[m][n], 0, 0, 0);                         \
        __builtin_amdgcn_s_setprio(0);                                         \
    } while (0)

    // fence: wave's ds ops done, barrier. No vmcnt drain - prefetch loads
    // stay in flight across phases.
#define PHASE_FENCE()                                                          \
    do {                                                                       \
        asm volatile("s_waitcnt lgkmcnt(0)" ::: "memory");                     \
        __builtin_amdgcn_s_barrier();                                          \
        asm volatile("" ::: "memory");                                         \
    } while (0)

#define ROTATE()                                                               \
    do { int t = cbase; cbase = rbase; rbase = wbase; wbase = t; } while (0)

    // prologue: tile0 -> b0; tile1 -> b1; x <- tile0 frags; p <- tile2
    LOADT(0);
    STORET(0);
    LOADT(1);
    PHASE_FENCE();            // b0 visible
    STORET(TSZ);              // tile1 -> b1
    LOADT(2);
    FRAG_READ(xa, xb, 0);     // tile0 frags -> x
    PHASE_FENCE();            // b1 visible
    int cbase = 0, rbase = TSZ, wbase = 2 * TSZ;

    for (int k = 0; k < NK; k += 2) {
        // phase k: compute x (tile k); prefetch y <- tile k+1 (stable buf);
        // store tile k+2 (reg set, loaded phase k-1); load tile k+3
        if (k + 1 < NK) FRAG_READ(ya, yb, rbase);
        MFMA_BLOCK(xa, xb);
        if (k + 2 < NK) STORET(wbase);
        if (k + 3 < NK) LOADT(k + 3);
        PHASE_FENCE();
        ROTATE();
        // phase k+1: compute y; prefetch x <- tile k+2; store k+3; load k+4
        if (k + 2 < NK) FRAG_READ(xa, xb, rbase);
        MFMA_BLOCK(ya, yb);
        if (k + 3 < NK) STORET(wbase);
        if (k + 4 < NK) LOADT(k + 4);
        PHASE_FENCE();
        ROTATE();
    }

    // norms: row's sumsq lives in its 4 seg-threads; xor 1,2 reduces in-group
    sqa += __shfl_xor(sqa, 1);
    sqa += __shfl_xor(sqa, 2);
    sqb += __shfl_xor(sqb, 1);
    sqb += __shfl_xor(sqb, 2);
    if (seg == 0) {
        tn[srow] = sqrtf(sqa);
        sn[srow] = sqrtf(sqb);
    }
    __syncthreads();

    float* outp = out + (size_t)b * NT * NS;
#pragma unroll
    for (int m = 0; m < 4; ++m) {
        const int lr0 = wr + m * 16 + lhi * 4;
#pragma unroll
        for (int n = 0; n < 2; ++n) {
            const int lc = wc + n * 16 + llo;
            const float snv = sn[lc];
            const int col = bs0 + lc;
#pragma unroll
            for (int j = 0; j < 4; ++j) {
                const float denom = fmaxf(tn[lr0 + j] * snv, 1e-10f);
                outp[(size_t)(bt0 + lr0 + j) * NS + col] =
                    acc[m][n][j] / denom * 0.5f + 0.5f;
            }
        }
    }
}

extern "C" void kernel_launch(void* const* d_in, const int* in_sizes, int n_in,
                              void* d_out, int out_size, void* d_ws, size_t ws_size,
                              hipStream_t stream) {
    const float* sup = (const float*)d_in[0]; // supports [32,512,1024]
    const float* tgt = (const float*)d_in[1]; // targets  [32,512,1024]
    float* out = (float*)d_out;               // [32,512,512] f32
    (void)in_sizes; (void)n_in; (void)out_size; (void)d_ws; (void)ws_size;
    paircos_mfma<<<dim3(16 * NBATCH), 512, 0, stream>>>(sup, tgt, out);
}

// Round 10
// 35.152 us; speedup vs baseline: 1.1530x; 1.1406x over previous
//
#include <hip/hip_runtime.h>
#include <hip/hip_bf16.h>

typedef __attribute__((ext_vector_type(8))) short short8;
typedef __attribute__((ext_vector_type(4))) float f32x4;

#define NBATCH 32
#define NT 512
#define NS 512
#define ND 1024
#define BM 128               /* target rows per tile */
#define BN 256               /* support rows per tile */
#define BK 32                /* elems per phase (one MFMA k-depth) */
#define NK (ND / BK)         /* 32 phases */

__device__ __forceinline__ short f2bf(float f) {
    union { __hip_bfloat16 h; short s; } u;
    u.h = __float2bfloat16(f);
    return u.s;
}

__device__ __forceinline__ short8 cvt8(float4 a, float4 b) {
    short8 r;
    r[0] = f2bf(a.x); r[1] = f2bf(a.y); r[2] = f2bf(a.z); r[3] = f2bf(a.w);
    r[4] = f2bf(b.x); r[5] = f2bf(b.y); r[6] = f2bf(b.z); r[7] = f2bf(b.w);
    return r;
}

__device__ __forceinline__ float ssq4(float s, float4 a) {
    return fmaf(a.x, a.x, fmaf(a.y, a.y, fmaf(a.z, a.z, fmaf(a.w, a.w, s))));
}

// FABRIC-TRAFFIC ROUND. r5..r9 (39.3-40.5us) were invariant across schedule
// structure (barrier count, issue order, frag prefetch, wave count) - the
// only invariant quantity was cache-fabric read traffic: 128x128 tiles
// re-read each input row 4x = 512MB reads ~ 14.3 TB/s at 39.7us, at the
// plausible L3/fabric ceiling (concurrent per-XCD working set 32MB >> 4MB
// L2, so re-reads are L3-served). This round: 128x256 tile -> B re-read
// 4x -> 2x, reads 512 -> 384MB (-27%). Grid 256 blocks = 1/CU (8 waves/CU;
// r6 showed the occupancy cost of this is only ~5%). launch_bounds(512,2)
// lifts the VGPR cap to 256 for the 64-reg accumulator (4x4 frags, wave =
// 64x64). Everything else is the r5 proven structure: BK=32, double-
// buffered LDS, single prefetch reg set (1-phase vmcnt distance; phases are
// 2x longer here), bf16 cvt once at staging, lgkmcnt(0)-only s_barrier
// fences (global loads never drained), swizzle (u + (row>>1))&3 both sides
// (measured 0 conflicts), fused row sum-of-squares (norms free),
// XCD-chunked 1D grid (256 % 8 == 0).
__global__ __launch_bounds__(512, 2)
void paircos_mfma(const float* __restrict__ sup, const float* __restrict__ tgt,
                  float* __restrict__ out) {
    __shared__ __align__(16) short As[2][BM * BK]; // targets tiles (8KB each)
    __shared__ __align__(16) short Bs[2][BN * BK]; // supports tiles (16KB each)
    __shared__ float tn[BM];
    __shared__ float sn[BN];

    const int tid = threadIdx.x;
    // XCD-chunked bijective swizzle (256 blocks)
    const int l    = blockIdx.x;
    const int wgid = (l & 7) * 32 + (l >> 3);
    const int b    = wgid >> 3;        // batch
    const int til  = wgid & 7;         // 4 t-tiles x 2 s-tiles
    const int bt0  = (til >> 1) * BM;
    const int bs0  = (til & 1) * BN;

    // staging: thread owns 8-elem segment seg of A row srow and B rows
    // srow, srow+128 (A: 128x4 = 512 assignments; B: 256x4 = 1024 = 2/thread)
    const int seg  = tid & 3;
    const int srow = tid >> 2; // 0..127

    const float* gA = tgt + (size_t)b * NT * ND + (size_t)(bt0 + srow) * ND + seg * 8;
    const float* gB = sup + (size_t)b * NS * ND + (size_t)(bs0 + srow) * ND + seg * 8;

    const int wave = tid >> 6;
    const int lane = tid & 63;
    const int wr  = (wave >> 2) * 64;  // 0 or 64
    const int wc  = (wave & 3) * 64;   // 0,64,128,192
    const int lhi = lane >> 4;         // 0..3 (k-group of 8)
    const int llo = lane & 15;

    f32x4 acc[4][4];
#pragma unroll
    for (int m = 0; m < 4; ++m)
#pragma unroll
        for (int n = 0; n < 4; ++n)
            acc[m][n] = (f32x4){0.f, 0.f, 0.f, 0.f};

    float sqa = 0.f, sqb0 = 0.f, sqb1 = 0.f;

    // single prefetch reg set (24 VGPR)
    float4 pA0, pA1, pB0, pB1, pB2, pB3;

    // staging LDS offsets (shorts); (srow+128)>>1 ≡ srow>>1 (mod 4)
    const int pu   = ((seg + (srow >> 1)) & 3) * 8;
    const int offw = srow * BK + pu;

#define LOADT(KK)                                                              \
    do {                                                                       \
        pA0 = *reinterpret_cast<const float4*>(gA + (KK) * BK);                \
        pA1 = *reinterpret_cast<const float4*>(gA + (KK) * BK + 4);            \
        pB0 = *reinterpret_cast<const float4*>(gB + (KK) * BK);                \
        pB1 = *reinterpret_cast<const float4*>(gB + (KK) * BK + 4);            \
        pB2 = *reinterpret_cast<const float4*>(gB + (KK) * BK + 128 * ND);     \
        pB3 = *reinterpret_cast<const float4*>(gB + (KK) * BK + 128 * ND + 4); \
    } while (0)

#define STORET(P)                                                              \
    do {                                                                       \
        sqa  = ssq4(ssq4(sqa,  pA0), pA1);                                     \
        *reinterpret_cast<short8*>(&As[P][offw]) = cvt8(pA0, pA1);             \
        sqb0 = ssq4(ssq4(sqb0, pB0), pB1);                                     \
        *reinterpret_cast<short8*>(&Bs[P][offw]) = cvt8(pB0, pB1);             \
        sqb1 = ssq4(ssq4(sqb1, pB2), pB3);                                     \
        *reinterpret_cast<short8*>(&Bs[P][offw + 128 * BK]) = cvt8(pB2, pB3);  \
    } while (0)

#define FRAG_READ(P)                                                           \
    do {                                                                       \
        _Pragma("unroll") for (int m = 0; m < 4; ++m) {                        \
            const int row = wr + m * 16 + llo;                                 \
            const int off = row * BK + (((lhi + (row >> 1)) & 3) * 8);         \
            af[m] = *reinterpret_cast<const short8*>(&As[P][off]);             \
        }                                                                      \
        _Pragma("unroll") for (int n = 0; n < 4; ++n) {                        \
            const int row = wc + n * 16 + llo;                                 \
            const int off = row * BK + (((lhi + (row >> 1)) & 3) * 8);         \
            bfr[n] = *reinterpret_cast<const short8*>(&Bs[P][off]);            \
        }                                                                      \
    } while (0)

#define MFMA_BLOCK()                                                           \
    do {                                                                       \
        __builtin_amdgcn_s_setprio(1);                                         \
        _Pragma("unroll") for (int m = 0; m < 4; ++m)                          \
            _Pragma("unroll") for (int n = 0; n < 4; ++n)                      \
                acc[m][n] = __builtin_amdgcn_mfma_f32_16x16x32_bf16(           \
                    af[m], bfr[n], acc[m][n], 0, 0, 0);                        \
        __builtin_amdgcn_s_setprio(0);                                         \
    } while (0)

    // fence: wave's ds ops done, barrier. No vmcnt drain - prefetch loads
    // stay in flight across phases.
#define PHASE_FENCE()                                                          \
    do {                                                                       \
        asm volatile("s_waitcnt lgkmcnt(0)" ::: "memory");                     \
        __builtin_amdgcn_s_barrier();                                          \
        asm volatile("" ::: "memory");                                         \
    } while (0)

    // prologue: tile0 -> buf0; set <- tile1
    LOADT(0);
    STORET(0);
    LOADT(1);
    PHASE_FENCE();

    for (int k = 0; k < NK; ++k) {
        const int cur = k & 1;
        short8 af[4], bfr[4];
        FRAG_READ(cur);                    // MFMA-feeding reads first
        if (k + 1 < NK) STORET(cur ^ 1);   // vmcnt wait = loads from phase k-1
        if (k + 2 < NK) LOADT(k + 2);      // refill set; waited next phase
        MFMA_BLOCK();
        PHASE_FENCE();
    }

    // norms: row's sumsq lives in its 4 seg-threads; xor 1,2 reduces in-group
    sqa  += __shfl_xor(sqa, 1);
    sqa  += __shfl_xor(sqa, 2);
    sqb0 += __shfl_xor(sqb0, 1);
    sqb0 += __shfl_xor(sqb0, 2);
    sqb1 += __shfl_xor(sqb1, 1);
    sqb1 += __shfl_xor(sqb1, 2);
    if (seg == 0) {
        tn[srow]       = sqrtf(sqa);
        sn[srow]       = sqrtf(sqb0);
        sn[srow + 128] = sqrtf(sqb1);
    }
    __syncthreads();

    float* outp = out + (size_t)b * NT * NS;
#pragma unroll
    for (int m = 0; m < 4; ++m) {
        const int lr0 = wr + m * 16 + lhi * 4;
#pragma unroll
        for (int n = 0; n < 4; ++n) {
            const int lc = wc + n * 16 + llo;
            const float snv = sn[lc];
            const int col = bs0 + lc;
#pragma unroll
            for (int j = 0; j < 4; ++j) {
                const float denom = fmaxf(tn[lr0 + j] * snv, 1e-10f);
                outp[(size_t)(bt0 + lr0 + j) * NS + col] =
                    acc[m][n][j] / denom * 0.5f + 0.5f;
            }
        }
    }
}

extern "C" void kernel_launch(void* const* d_in, const int* in_sizes, int n_in,
                              void* d_out, int out_size, void* d_ws, size_t ws_size,
                              hipStream_t stream) {
    const float* sup = (const float*)d_in[0]; // supports [32,512,1024]
    const float* tgt = (const float*)d_in[1]; // targets  [32,512,1024]
    float* out = (float*)d_out;               // [32,512,512] f32
    (void)in_sizes; (void)n_in; (void)out_size; (void)d_ws; (void)ws_size;
    paircos_mfma<<<dim3(32 * 8), 512, 0, stream>>>(sup, tgt, out);
}